// Round 7
// baseline (1116.575 us; speedup 1.0000x reference)
//
#include <hip/hip_runtime.h>

#define D_IN 256
#define D_HID 512
#define D_OUT 256
#define LN_EPS 1e-5f
#define NBLK 960          // mega-kernel grid: 4 blocks/CU capacity is 1024 -> 960 leaves slack
#define NTHR (NBLK * 256)

typedef __attribute__((ext_vector_type(8))) short bf16x8;
typedef __attribute__((ext_vector_type(4))) float f32x4;

__device__ __forceinline__ ushort f2bf(float x) {
    union { float f; unsigned u; } c; c.f = x;
    unsigned r = c.u + 0x7FFFu + ((c.u >> 16) & 1u);   // round-to-nearest-even
    return (ushort)(r >> 16);
}
__device__ __forceinline__ float bf2f(unsigned b) {
    union { unsigned u; float f; } c; c.u = b << 16;
    return c.f;
}

// ---------------------------------------------------------------------------
// device-scope grid barrier (counter-per-barrier, zeroed by the pre-memset).
// Safe: __launch_bounds__(256,4) caps VGPR at 128 -> >=4 blocks/CU resident;
// grid NBLK=960 < 4*256=1024 capacity. __threadfence() = agent-scope fence
// (L2 writeback/inv) for cross-XCD visibility of non-atomic data (G16).
// ---------------------------------------------------------------------------
__device__ __forceinline__ void gbar(int* bar, int k) {
    __threadfence();                  // release: my writes visible device-wide
    __syncthreads();
    if (threadIdx.x == 0) {
        atomicAdd(&bar[k], 1);
        while (atomicAdd(&bar[k], 0) < NBLK) __builtin_amdgcn_s_sleep(2);
    }
    __syncthreads();
    __threadfence();                  // acquire: don't read stale lines
}

// ---------------------------------------------------------------------------
// MEGA: casts + hist/rank | scan(chunk) | scan(base) | fill | gather-aggregate
// One launch replaces 5. All phases grid-stride over NBLK*256 threads.
// CSR trick: offs[] holds the exclusive scan WITHIN its 256-node chunk and
// bsum[] the exclusive chunk bases; readers use offsF(n)=bsum[n>>8]+offs[n],
// skipping the base-add phase entirely.
// ---------------------------------------------------------------------------
__global__ __launch_bounds__(256, 4) void mega_kernel(
    const float* __restrict__ v, const float* __restrict__ w1,
    const float* __restrict__ w2, ushort* __restrict__ vb,
    ushort* __restrict__ w1p, ushort* __restrict__ w2p,
    const int* __restrict__ src, const int* __restrict__ dst,
    const float* __restrict__ ew, const float* __restrict__ eps_p,
    int* __restrict__ rank, int* __restrict__ cnt, int* __restrict__ bar,
    int* __restrict__ offs, int* __restrict__ bsum, int2* __restrict__ perm,
    ushort* __restrict__ aggb, int N, int E, int n4v, int nch) {
    __shared__ int s[256];
    int t = threadIdx.x, b = blockIdx.x;
    int tid = b * 256 + t;

    // ---------------- P0: casts + packed weights + hist/rank ----------------
    for (int i = tid; i < n4v; i += NTHR) {
        float4 x = ((const float4*)v)[i];
        ((ushort4*)vb)[i] = make_ushort4(f2bf(x.x), f2bf(x.y), f2bf(x.z), f2bf(x.w));
    }
    for (int j = tid; j < 65536; j += NTHR) {
        if (j < 32768) {                // w1: [512][256] fp32
            int f = j * 4;
            int row = f >> 8, col = f & 255;
            float4 x = ((const float4*)w1)[j];
            int rb = row >> 4, fr = row & 15;
            int kb32 = col >> 5, q = (col & 31) >> 3, e = col & 7;
            int chunk = (kb32 * 32 + rb) * 64 + q * 16 + fr;
            *(ushort4*)(w1p + chunk * 8 + e) =
                make_ushort4(f2bf(x.x), f2bf(x.y), f2bf(x.z), f2bf(x.w));
        } else {                        // w2: [256][512] fp32
            int k = j - 32768;
            int f = k * 4;
            int row = f >> 9, col = f & 511;
            float4 x = ((const float4*)w2)[k];
            int rb = row >> 4, fr = row & 15;
            int kb32 = col >> 5, q = (col & 31) >> 3, e = col & 7;
            int chunk = (kb32 * 16 + rb) * 64 + q * 16 + fr;
            *(ushort4*)(w2p + chunk * 8 + e) =
                make_ushort4(f2bf(x.x), f2bf(x.y), f2bf(x.z), f2bf(x.w));
        }
    }
    for (int e = tid; e < E; e += NTHR)
        rank[e] = atomicAdd(&cnt[dst[e]], 1);

    gbar(bar, 0);

    // ---------------- P1: per-chunk exclusive scan (nch blocks) ----------------
    if (b < nch) {
        int i = b * 256 + t;
        int x = cnt[i];                 // i < nch*256 <= N+256, zeroed tail
        s[t] = x;
        __syncthreads();
        for (int o = 1; o < 256; o <<= 1) {
            int u = (t >= o) ? s[t - o] : 0;
            __syncthreads();
            s[t] += u;
            __syncthreads();
        }
        offs[i] = s[t] - x;             // exclusive within chunk
        if (t == 255) bsum[b] = s[t];   // chunk total
    }
    gbar(bar, 1);

    // ---------------- P2: exclusive scan of chunk totals (block 0) ----------------
    if (b == 0) {
        int x = (t < nch) ? bsum[t] : 0;
        s[t] = x;
        __syncthreads();
        for (int o = 1; o < 256; o <<= 1) {
            int u = (t >= o) ? s[t - o] : 0;
            __syncthreads();
            s[t] += u;
            __syncthreads();
        }
        bsum[t] = s[t] - x;             // exclusive chunk base
    }
    gbar(bar, 2);

    // ---------------- P3: counting-sort fill (no atomics) ----------------
    for (int e = tid; e < E; e += NTHR) {
        int d = dst[e];
        int p = bsum[d >> 8] + offs[d] + rank[e];
        perm[p] = make_int2(src[e], __float_as_int(ew[e]));
    }
    gbar(bar, 3);

    // ---------------- P4: gather-aggregate, one wave per node ----------------
    {
        const float eps = eps_p[0];
        int lane = t & 63;
        int wid = b * 4 + (t >> 6);
        for (int node = wid; node < N; node += NBLK * 4) {
            int beg = bsum[node >> 8] + offs[node];
            int m = node + 1;
            int end = (m < nch * 256) ? (bsum[m >> 8] + offs[m]) : E;
            float a0 = 0.f, a1 = 0.f, a2 = 0.f, a3 = 0.f;
            float c0 = 0.f, c1 = 0.f, c2 = 0.f, c3 = 0.f;

            int i = beg;
            for (; i + 8 <= end; i += 8) {
                int2 p0 = perm[i + 0], p1 = perm[i + 1], p2 = perm[i + 2], p3 = perm[i + 3];
                int2 p4 = perm[i + 4], p5 = perm[i + 5], p6 = perm[i + 6], p7 = perm[i + 7];
                float w0 = __int_as_float(p0.y), w1_ = __int_as_float(p1.y);
                float w2_ = __int_as_float(p2.y), w3 = __int_as_float(p3.y);
                float w4 = __int_as_float(p4.y), w5 = __int_as_float(p5.y);
                float w6 = __int_as_float(p6.y), w7 = __int_as_float(p7.y);
                ushort4 r0 = ((const ushort4*)(vb + (size_t)p0.x * D_IN))[lane];
                ushort4 r1 = ((const ushort4*)(vb + (size_t)p1.x * D_IN))[lane];
                ushort4 r2 = ((const ushort4*)(vb + (size_t)p2.x * D_IN))[lane];
                ushort4 r3 = ((const ushort4*)(vb + (size_t)p3.x * D_IN))[lane];
                ushort4 r4 = ((const ushort4*)(vb + (size_t)p4.x * D_IN))[lane];
                ushort4 r5 = ((const ushort4*)(vb + (size_t)p5.x * D_IN))[lane];
                ushort4 r6 = ((const ushort4*)(vb + (size_t)p6.x * D_IN))[lane];
                ushort4 r7 = ((const ushort4*)(vb + (size_t)p7.x * D_IN))[lane];
                a0 += w0 * bf2f(r0.x) + w1_ * bf2f(r1.x) + w2_ * bf2f(r2.x) + w3 * bf2f(r3.x);
                a1 += w0 * bf2f(r0.y) + w1_ * bf2f(r1.y) + w2_ * bf2f(r2.y) + w3 * bf2f(r3.y);
                a2 += w0 * bf2f(r0.z) + w1_ * bf2f(r1.z) + w2_ * bf2f(r2.z) + w3 * bf2f(r3.z);
                a3 += w0 * bf2f(r0.w) + w1_ * bf2f(r1.w) + w2_ * bf2f(r2.w) + w3 * bf2f(r3.w);
                c0 += w4 * bf2f(r4.x) + w5 * bf2f(r5.x) + w6 * bf2f(r6.x) + w7 * bf2f(r7.x);
                c1 += w4 * bf2f(r4.y) + w5 * bf2f(r5.y) + w6 * bf2f(r6.y) + w7 * bf2f(r7.y);
                c2 += w4 * bf2f(r4.z) + w5 * bf2f(r5.z) + w6 * bf2f(r6.z) + w7 * bf2f(r7.z);
                c3 += w4 * bf2f(r4.w) + w5 * bf2f(r5.w) + w6 * bf2f(r6.w) + w7 * bf2f(r7.w);
            }
            for (; i + 4 <= end; i += 4) {
                int2 p0 = perm[i + 0], p1 = perm[i + 1], p2 = perm[i + 2], p3 = perm[i + 3];
                float w0 = __int_as_float(p0.y), w1_ = __int_as_float(p1.y);
                float w2_ = __int_as_float(p2.y), w3 = __int_as_float(p3.y);
                ushort4 r0 = ((const ushort4*)(vb + (size_t)p0.x * D_IN))[lane];
                ushort4 r1 = ((const ushort4*)(vb + (size_t)p1.x * D_IN))[lane];
                ushort4 r2 = ((const ushort4*)(vb + (size_t)p2.x * D_IN))[lane];
                ushort4 r3 = ((const ushort4*)(vb + (size_t)p3.x * D_IN))[lane];
                a0 += w0 * bf2f(r0.x) + w1_ * bf2f(r1.x) + w2_ * bf2f(r2.x) + w3 * bf2f(r3.x);
                a1 += w0 * bf2f(r0.y) + w1_ * bf2f(r1.y) + w2_ * bf2f(r2.y) + w3 * bf2f(r3.y);
                a2 += w0 * bf2f(r0.z) + w1_ * bf2f(r1.z) + w2_ * bf2f(r2.z) + w3 * bf2f(r3.z);
                a3 += w0 * bf2f(r0.w) + w1_ * bf2f(r1.w) + w2_ * bf2f(r2.w) + w3 * bf2f(r3.w);
            }
            for (; i < end; ++i) {
                int2 p = perm[i];
                float we = __int_as_float(p.y);
                ushort4 rr = ((const ushort4*)(vb + (size_t)p.x * D_IN))[lane];
                a0 += we * bf2f(rr.x); a1 += we * bf2f(rr.y);
                a2 += we * bf2f(rr.z); a3 += we * bf2f(rr.w);
            }
            a0 += c0; a1 += c1; a2 += c2; a3 += c3;
            ushort4 mv = ((const ushort4*)(vb + (size_t)node * D_IN))[lane];
            a0 += eps * bf2f(mv.x); a1 += eps * bf2f(mv.y);
            a2 += eps * bf2f(mv.z); a3 += eps * bf2f(mv.w);
            ((ushort4*)(aggb + (size_t)node * D_IN))[lane] =
                make_ushort4(f2bf(a0), f2bf(a1), f2bf(a2), f2bf(a3));
        }
    }
}

// ---------------------------------------------------------------------------
// Fused MLP, 64-row tile, reg-pipelined K-loops (unchanged from R6: 59.4us).
// ---------------------------------------------------------------------------
#define HS_IDX(row, col) ((row) * 512 + ((col) ^ (((row) & 7) << 3)))
#define AT_IDX(row, col) ((row) * 256 + ((col) ^ (((row) & 7) << 3)))

__global__ __launch_bounds__(256, 2) void mlp_kernel(
    const ushort* __restrict__ A, const ushort* __restrict__ w1p,
    const ushort* __restrict__ w2p,
    const float* __restrict__ b1, const float* __restrict__ g1, const float* __restrict__ be1,
    const float* __restrict__ b2, const float* __restrict__ g2, const float* __restrict__ be2,
    float* __restrict__ out, int N) {
    __shared__ ushort hs[32768];      // 64 KB
    __shared__ float redf[640];

    int t = threadIdx.x;
    int w = t >> 6, lane = t & 63;
    int row0 = blockIdx.x * 64;
    int fr = lane & 15, q = lane >> 4, kb = q * 8;

    // ---- stage A-tile once: 8 coalesced 1KB loads/wave, source-swizzled ----
    #pragma unroll
    for (int j = 0; j < 8; ++j) {
        int p = (w * 8 + j) * 64 + lane;
        int row = p >> 5, cbs = p & 31;
        int colblk = cbs ^ (row & 7);
        int ar = row0 + row; if (ar > N - 1) ar = N - 1;
        const ushort* gp = A + (size_t)ar * D_IN + colblk * 8;
        __builtin_amdgcn_global_load_lds(
            (const __attribute__((address_space(1))) void*)gp,
            (__attribute__((address_space(3))) void*)(&hs[(w * 8 + j) * 512]),
            16, 0, 0);
    }

    bf16x8 bfb[2][8];
    #pragma unroll
    for (int c = 0; c < 8; ++c)
        bfb[0][c] = *(const bf16x8*)(w1p + (size_t)((w * 8 + c) * 64 + lane) * 8);

    __syncthreads();

    f32x4 acc[4][8];
    #pragma unroll
    for (int m = 0; m < 4; ++m)
        #pragma unroll
        for (int c = 0; c < 8; ++c) {
            f32x4 z = {0.f, 0.f, 0.f, 0.f};
            acc[m][c] = z;
        }

    #pragma unroll
    for (int ks = 0; ks < 8; ++ks) {
        const int cur = ks & 1, nxt = cur ^ 1;
        if (ks < 7) {
            #pragma unroll
            for (int c = 0; c < 8; ++c)
                bfb[nxt][c] = *(const bf16x8*)(w1p +
                    (size_t)(((ks + 1) * 32 + w * 8 + c) * 64 + lane) * 8);
        }
        bf16x8 af[4];
        #pragma unroll
        for (int m = 0; m < 4; ++m)
            af[m] = *(const bf16x8*)&hs[AT_IDX(m * 16 + fr, ks * 32 + kb)];
        #pragma unroll
        for (int m = 0; m < 4; ++m)
            #pragma unroll
            for (int c = 0; c < 8; ++c)
                acc[m][c] = __builtin_amdgcn_mfma_f32_16x16x32_bf16(af[m], bfb[cur][c], acc[m][c], 0, 0, 0);
    }

    {
        float bi[8], gg[8], bb[8];
        #pragma unroll
        for (int c = 0; c < 8; ++c) {
            int col = w * 128 + c * 16 + fr;
            bi[c] = b1[col]; gg[c] = g1[col]; bb[c] = be1[col];
        }
        #pragma unroll
        for (int m = 0; m < 4; ++m) {
            #pragma unroll
            for (int r = 0; r < 4; ++r) {
                float s = 0.f, sq = 0.f;
                #pragma unroll
                for (int c = 0; c < 8; ++c) {
                    float x = acc[m][c][r] + bi[c];
                    acc[m][c][r] = x;
                    s += x; sq += x * x;
                }
                #pragma unroll
                for (int o = 1; o < 16; o <<= 1) {
                    s  += __shfl_xor(s, o, 64);
                    sq += __shfl_xor(sq, o, 64);
                }
                if (fr == 0) {
                    int row = m * 16 + q * 4 + r;
                    redf[row * 4 + w]       = s;
                    redf[256 + row * 4 + w] = sq;
                }
            }
        }
        __syncthreads();
        if (t < 64) {
            float s  = redf[t * 4 + 0] + redf[t * 4 + 1] + redf[t * 4 + 2] + redf[t * 4 + 3];
            float sq = redf[256 + t * 4 + 0] + redf[256 + t * 4 + 1] +
                       redf[256 + t * 4 + 2] + redf[256 + t * 4 + 3];
            float mu = s / (float)D_HID;
            float var = sq / (float)D_HID - mu * mu;
            redf[512 + t] = mu;
            redf[576 + t] = rsqrtf(var + LN_EPS);
        }
        __syncthreads();
        #pragma unroll
        for (int m = 0; m < 4; ++m) {
            #pragma unroll
            for (int r = 0; r < 4; ++r) {
                int row = m * 16 + q * 4 + r;
                float mu = redf[512 + row], rs = redf[576 + row];
                #pragma unroll
                for (int c = 0; c < 8; ++c) {
                    int col = w * 128 + c * 16 + fr;
                    float y = (acc[m][c][r] - mu) * rs * gg[c] + bb[c];
                    hs[HS_IDX(row, col)] = f2bf(fmaxf(y, 0.f));
                }
            }
        }
    }

    bf16x8 bf2b[2][4][2];
    #pragma unroll
    for (int c = 0; c < 4; ++c)
        #pragma unroll
        for (int h = 0; h < 2; ++h)
            bf2b[0][c][h] = *(const bf16x8*)(w2p +
                (size_t)(((0 + h) * 16 + w * 4 + c) * 64 + lane) * 8);

    __syncthreads();

    f32x4 acc2[4][4];
    #pragma unroll
    for (int m = 0; m < 4; ++m)
        #pragma unroll
        for (int c = 0; c < 4; ++c) {
            f32x4 z = {0.f, 0.f, 0.f, 0.f};
            acc2[m][c] = z;
        }

    #pragma unroll
    for (int s2 = 0; s2 < 8; ++s2) {
        const int cur = s2 & 1, nxt = cur ^ 1;
        if (s2 < 7) {
            #pragma unroll
            for (int c = 0; c < 4; ++c)
                #pragma unroll
                for (int h = 0; h < 2; ++h)
                    bf2b[nxt][c][h] = *(const bf16x8*)(w2p +
                        (size_t)(((2 * (s2 + 1) + h) * 16 + w * 4 + c) * 64 + lane) * 8);
        }
        bf16x8 af2[4][2];
        #pragma unroll
        for (int m = 0; m < 4; ++m)
            #pragma unroll
            for (int h = 0; h < 2; ++h)
                af2[m][h] = *(const bf16x8*)&hs[HS_IDX(m * 16 + fr, s2 * 64 + h * 32 + kb)];
        #pragma unroll
        for (int m = 0; m < 4; ++m)
            #pragma unroll
            for (int c = 0; c < 4; ++c)
                #pragma unroll
                for (int h = 0; h < 2; ++h)
                    acc2[m][c] = __builtin_amdgcn_mfma_f32_16x16x32_bf16(af2[m][h], bf2b[cur][c][h], acc2[m][c], 0, 0, 0);
    }

    {
        float bi[4], gg[4], bb[4];
        #pragma unroll
        for (int c = 0; c < 4; ++c) {
            int col = w * 64 + c * 16 + fr;
            bi[c] = b2[col]; gg[c] = g2[col]; bb[c] = be2[col];
        }
        #pragma unroll
        for (int m = 0; m < 4; ++m) {
            #pragma unroll
            for (int r = 0; r < 4; ++r) {
                float s = 0.f, sq = 0.f;
                #pragma unroll
                for (int c = 0; c < 4; ++c) {
                    float x = acc2[m][c][r] + bi[c];
                    acc2[m][c][r] = x;
                    s += x; sq += x * x;
                }
                #pragma unroll
                for (int o = 1; o < 16; o <<= 1) {
                    s  += __shfl_xor(s, o, 64);
                    sq += __shfl_xor(sq, o, 64);
                }
                if (fr == 0) {
                    int row = m * 16 + q * 4 + r;
                    redf[row * 4 + w]       = s;
                    redf[256 + row * 4 + w] = sq;
                }
            }
        }
        __syncthreads();
        if (t < 64) {
            float s  = redf[t * 4 + 0] + redf[t * 4 + 1] + redf[t * 4 + 2] + redf[t * 4 + 3];
            float sq = redf[256 + t * 4 + 0] + redf[256 + t * 4 + 1] +
                       redf[256 + t * 4 + 2] + redf[256 + t * 4 + 3];
            float mu = s / (float)D_OUT;
            float var = sq / (float)D_OUT - mu * mu;
            redf[512 + t] = mu;
            redf[576 + t] = rsqrtf(var + LN_EPS);
        }
        __syncthreads();
        #pragma unroll
        for (int m = 0; m < 4; ++m) {
            #pragma unroll
            for (int r = 0; r < 4; ++r) {
                int row = m * 16 + q * 4 + r;
                int grow = row0 + row;
                if (grow >= N) continue;
                float mu = redf[512 + row], rs = redf[576 + row];
                #pragma unroll
                for (int c = 0; c < 4; ++c) {
                    int col = w * 64 + c * 16 + fr;
                    float y = (acc2[m][c][r] - mu) * rs * gg[c] + bb[c];
                    out[(size_t)grow * D_OUT + col] = fmaxf(y, 0.f);
                }
            }
        }
    }
}

// ---------------------------------------------------------------------------
extern "C" void kernel_launch(void* const* d_in, const int* in_sizes, int n_in,
                              void* d_out, int out_size, void* d_ws, size_t ws_size,
                              hipStream_t stream) {
    const float* v     = (const float*)d_in[0];
    const float* ew    = (const float*)d_in[1];
    const float* eps   = (const float*)d_in[2];
    const float* w1    = (const float*)d_in[3];
    const float* b1    = (const float*)d_in[4];
    const float* g1    = (const float*)d_in[5];
    const float* beta1 = (const float*)d_in[6];
    const float* w2    = (const float*)d_in[7];
    const float* b2    = (const float*)d_in[8];
    const float* g2    = (const float*)d_in[9];
    const float* beta2 = (const float*)d_in[10];
    const int*   src   = (const int*)d_in[11];
    const int*   dst   = (const int*)d_in[12];

    int N = in_sizes[0] / D_IN;     // 50000
    int E = in_sizes[1];            // 800000

    float* out = (float*)d_out;

    // workspace layout (256B-aligned chunks)
    char* ws = (char*)d_ws;
    size_t off = 0;
    ushort* vb   = (ushort*)(ws + off); off += (size_t)N * D_IN * 2;            // 25.6 MB
    ushort* aggb = (ushort*)(ws + off); off += (size_t)N * D_IN * 2;            // 25.6 MB
    ushort* w1p  = (ushort*)(ws + off); off += (size_t)D_HID * D_IN * 2;        // 256 KB
    ushort* w2p  = (ushort*)(ws + off); off += (size_t)D_OUT * D_HID * 2;       // 256 KB
    int* offs     = (int*)(ws + off); off += (size_t)(N + 256) * 4;
    int* cnt      = (int*)(ws + off); off += (size_t)(N + 256) * 4;             // zeroed
    int* bar      = (int*)(ws + off); off += 64 * 4;                            // zeroed
    int* bsum     = (int*)(ws + off); off += 1024;
    int* rank     = (int*)(ws + off); off += (size_t)E * 4;                     // 3.2 MB
    int2* perm    = (int2*)(ws + off); off += (size_t)E * 8;                    // 6.4 MB

    int n4v = N * (D_IN / 4);
    int nch = (N + 255) / 256;       // 196 scan chunks (must be <= 256)

    // 0) zero histogram + barrier counters (cnt and bar are contiguous)
    hipMemsetAsync(cnt, 0, ((size_t)(N + 256) + 64) * 4, stream);

    // 1) mega: casts + hist/rank | scan | base-scan | fill | gather-aggregate
    mega_kernel<<<NBLK, 256, 0, stream>>>(v, w1, w2, vb, w1p, w2p,
                                          src, dst, ew, eps,
                                          rank, cnt, bar, offs, bsum, perm,
                                          aggb, N, E, n4v, nch);

    // 2) fused MLP
    int mblocks = (N + 63) / 64;
    mlp_kernel<<<mblocks, 256, 0, stream>>>(aggb, w1p, w2p,
                                            b1, g1, beta1, b2, g2, beta2, out, N);
}

// Round 8
// 867.829 us; speedup vs baseline: 1.2866x; 1.2866x over previous
//
#include <hip/hip_runtime.h>

#define D_IN 256
#define D_HID 512
#define D_OUT 256
#define LN_EPS 1e-5f
#define NBLK 960          // mega grid: 4 blocks/CU capacity (1024) > 960 -> co-resident
#define NTHR (NBLK * 256)

typedef __attribute__((ext_vector_type(8))) short bf16x8;
typedef __attribute__((ext_vector_type(4))) float f32x4;

__device__ __forceinline__ ushort f2bf(float x) {
    union { float f; unsigned u; } c; c.f = x;
    unsigned r = c.u + 0x7FFFu + ((c.u >> 16) & 1u);   // round-to-nearest-even
    return (ushort)(r >> 16);
}
__device__ __forceinline__ float bf2f(unsigned b) {
    union { unsigned u; float f; } c; c.u = b << 16;
    return c.f;
}

// ---------------------------------------------------------------------------
// device-scope grid barrier, LOAD-polling (R7's RMW-poll serialized through
// the home L2 and cost ~200us/barrier; atomic loads are concurrent).
// Co-residency: __launch_bounds__(256,4) caps VGPR<=128 -> >=4 blocks/CU;
// NBLK=960 < 1024 capacity. __threadfence (agent fence) by all threads
// handles cross-XCD visibility of non-atomic data (G16) - verified in R7.
// ---------------------------------------------------------------------------
__device__ __forceinline__ void gbar(int* bar, int k) {
    __threadfence();                  // release: block's writes device-visible
    __syncthreads();
    if (threadIdx.x == 0) {
        __hip_atomic_fetch_add(&bar[k], 1, __ATOMIC_ACQ_REL, __HIP_MEMORY_SCOPE_AGENT);
        while (__hip_atomic_load(&bar[k], __ATOMIC_ACQUIRE, __HIP_MEMORY_SCOPE_AGENT) < NBLK)
            __builtin_amdgcn_s_sleep(16);
    }
    __syncthreads();
    __threadfence();                  // acquire: no stale reads
}

// ---------------------------------------------------------------------------
// MEGA (P0-P3 only; gather stays standalone for TLP - R5 lesson):
//   P0: casts + packed weights + hist/rank   (cnt pre-zeroed by memset)
//   P1: per-256-chunk exclusive scan -> offs (chunk-local), bsum (totals)
//   P2: exclusive scan of chunk totals -> bsum (bases), block 0
//   P3: counting-sort fill, no atomics: slot = bsum[d>>8]+offs[d]+rank[e]
// Readers use the (bsum, offs) pair directly - no finalize pass.
// ---------------------------------------------------------------------------
__global__ __launch_bounds__(256, 4) void mega_kernel(
    const float* __restrict__ v, const float* __restrict__ w1,
    const float* __restrict__ w2, ushort* __restrict__ vb,
    ushort* __restrict__ w1p, ushort* __restrict__ w2p,
    const int* __restrict__ src, const int* __restrict__ dst,
    const float* __restrict__ ew,
    int* __restrict__ rank, int* __restrict__ cnt, int* __restrict__ bar,
    int* __restrict__ offs, int* __restrict__ bsum, int2* __restrict__ perm,
    int N, int E, int n4v, int nch) {
    __shared__ int s[256];
    int t = threadIdx.x, b = blockIdx.x;
    int tid = b * 256 + t;

    // ---------------- P0: casts + packed weights + hist/rank ----------------
    for (int i = tid; i < n4v; i += NTHR) {
        float4 x = ((const float4*)v)[i];
        ((ushort4*)vb)[i] = make_ushort4(f2bf(x.x), f2bf(x.y), f2bf(x.z), f2bf(x.w));
    }
    for (int j = tid; j < 65536; j += NTHR) {
        if (j < 32768) {                // w1: [512][256] fp32
            int f = j * 4;
            int row = f >> 8, col = f & 255;
            float4 x = ((const float4*)w1)[j];
            int rb = row >> 4, fr = row & 15;
            int kb32 = col >> 5, q = (col & 31) >> 3, e = col & 7;
            int chunk = (kb32 * 32 + rb) * 64 + q * 16 + fr;
            *(ushort4*)(w1p + chunk * 8 + e) =
                make_ushort4(f2bf(x.x), f2bf(x.y), f2bf(x.z), f2bf(x.w));
        } else {                        // w2: [256][512] fp32
            int k = j - 32768;
            int f = k * 4;
            int row = f >> 9, col = f & 511;
            float4 x = ((const float4*)w2)[k];
            int rb = row >> 4, fr = row & 15;
            int kb32 = col >> 5, q = (col & 31) >> 3, e = col & 7;
            int chunk = (kb32 * 16 + rb) * 64 + q * 16 + fr;
            *(ushort4*)(w2p + chunk * 8 + e) =
                make_ushort4(f2bf(x.x), f2bf(x.y), f2bf(x.z), f2bf(x.w));
        }
    }
    for (int e = tid; e < E; e += NTHR)
        rank[e] = atomicAdd(&cnt[dst[e]], 1);

    gbar(bar, 0);

    // ---------------- P1: per-chunk exclusive scan (nch blocks) ----------------
    if (b < nch) {
        int i = b * 256 + t;
        int x = cnt[i];                 // i < nch*256 <= N+256, zeroed tail
        s[t] = x;
        __syncthreads();
        for (int o = 1; o < 256; o <<= 1) {
            int u = (t >= o) ? s[t - o] : 0;
            __syncthreads();
            s[t] += u;
            __syncthreads();
        }
        offs[i] = s[t] - x;             // exclusive within chunk
        if (t == 255) bsum[b] = s[t];   // chunk total
    }
    gbar(bar, 1);

    // ---------------- P2: exclusive scan of chunk totals (block 0) ----------------
    if (b == 0) {
        int x = (t < nch) ? bsum[t] : 0;
        s[t] = x;
        __syncthreads();
        for (int o = 1; o < 256; o <<= 1) {
            int u = (t >= o) ? s[t - o] : 0;
            __syncthreads();
            s[t] += u;
            __syncthreads();
        }
        bsum[t] = s[t] - x;             // exclusive chunk base
    }
    gbar(bar, 2);

    // ---------------- P3: counting-sort fill (no atomics) ----------------
    for (int e = tid; e < E; e += NTHR) {
        int d = dst[e];
        int p = bsum[d >> 8] + offs[d] + rank[e];
        perm[p] = make_int2(src[e], __float_as_int(ew[e]));
    }
}

// ---------------------------------------------------------------------------
// agg_bf16[n] = bf16( eps*vb[n] + sum_{e:dst=n} w_e * vb[src_e] )
// one wave/node, 12.5k blocks for TLP (R6: 59.6us, 3.6 TB/s, occ 60%).
// beg/end from the (bsum, offs) split; node+1 <= N < nch*256 always valid.
// ---------------------------------------------------------------------------
__global__ __launch_bounds__(256) void aggregate_kernel(
    const ushort* __restrict__ vb, const float* __restrict__ eps_p,
    const int* __restrict__ offs, const int* __restrict__ bsum,
    const int2* __restrict__ perm, ushort* __restrict__ aggb, int N) {
    int node = blockIdx.x * 4 + (threadIdx.x >> 6);
    if (node >= N) return;
    int lane = threadIdx.x & 63;
    int beg = bsum[node >> 8] + offs[node];
    int m1 = node + 1;
    int end = bsum[m1 >> 8] + offs[m1];
    float a0 = 0.f, a1 = 0.f, a2 = 0.f, a3 = 0.f;
    float c0 = 0.f, c1 = 0.f, c2 = 0.f, c3 = 0.f;

    int i = beg;
    for (; i + 8 <= end; i += 8) {
        int2 p0 = perm[i + 0], p1 = perm[i + 1], p2 = perm[i + 2], p3 = perm[i + 3];
        int2 p4 = perm[i + 4], p5 = perm[i + 5], p6 = perm[i + 6], p7 = perm[i + 7];
        float w0 = __int_as_float(p0.y), w1 = __int_as_float(p1.y);
        float w2 = __int_as_float(p2.y), w3 = __int_as_float(p3.y);
        float w4 = __int_as_float(p4.y), w5 = __int_as_float(p5.y);
        float w6 = __int_as_float(p6.y), w7 = __int_as_float(p7.y);
        ushort4 r0 = ((const ushort4*)(vb + (size_t)p0.x * D_IN))[lane];
        ushort4 r1 = ((const ushort4*)(vb + (size_t)p1.x * D_IN))[lane];
        ushort4 r2 = ((const ushort4*)(vb + (size_t)p2.x * D_IN))[lane];
        ushort4 r3 = ((const ushort4*)(vb + (size_t)p3.x * D_IN))[lane];
        ushort4 r4 = ((const ushort4*)(vb + (size_t)p4.x * D_IN))[lane];
        ushort4 r5 = ((const ushort4*)(vb + (size_t)p5.x * D_IN))[lane];
        ushort4 r6 = ((const ushort4*)(vb + (size_t)p6.x * D_IN))[lane];
        ushort4 r7 = ((const ushort4*)(vb + (size_t)p7.x * D_IN))[lane];
        a0 += w0 * bf2f(r0.x) + w1 * bf2f(r1.x) + w2 * bf2f(r2.x) + w3 * bf2f(r3.x);
        a1 += w0 * bf2f(r0.y) + w1 * bf2f(r1.y) + w2 * bf2f(r2.y) + w3 * bf2f(r3.y);
        a2 += w0 * bf2f(r0.z) + w1 * bf2f(r1.z) + w2 * bf2f(r2.z) + w3 * bf2f(r3.z);
        a3 += w0 * bf2f(r0.w) + w1 * bf2f(r1.w) + w2 * bf2f(r2.w) + w3 * bf2f(r3.w);
        c0 += w4 * bf2f(r4.x) + w5 * bf2f(r5.x) + w6 * bf2f(r6.x) + w7 * bf2f(r7.x);
        c1 += w4 * bf2f(r4.y) + w5 * bf2f(r5.y) + w6 * bf2f(r6.y) + w7 * bf2f(r7.y);
        c2 += w4 * bf2f(r4.z) + w5 * bf2f(r5.z) + w6 * bf2f(r6.z) + w7 * bf2f(r7.z);
        c3 += w4 * bf2f(r4.w) + w5 * bf2f(r5.w) + w6 * bf2f(r6.w) + w7 * bf2f(r7.w);
    }
    for (; i + 4 <= end; i += 4) {
        int2 p0 = perm[i + 0], p1 = perm[i + 1], p2 = perm[i + 2], p3 = perm[i + 3];
        float w0 = __int_as_float(p0.y), w1 = __int_as_float(p1.y);
        float w2 = __int_as_float(p2.y), w3 = __int_as_float(p3.y);
        ushort4 r0 = ((const ushort4*)(vb + (size_t)p0.x * D_IN))[lane];
        ushort4 r1 = ((const ushort4*)(vb + (size_t)p1.x * D_IN))[lane];
        ushort4 r2 = ((const ushort4*)(vb + (size_t)p2.x * D_IN))[lane];
        ushort4 r3 = ((const ushort4*)(vb + (size_t)p3.x * D_IN))[lane];
        a0 += w0 * bf2f(r0.x) + w1 * bf2f(r1.x) + w2 * bf2f(r2.x) + w3 * bf2f(r3.x);
        a1 += w0 * bf2f(r0.y) + w1 * bf2f(r1.y) + w2 * bf2f(r2.y) + w3 * bf2f(r3.y);
        a2 += w0 * bf2f(r0.z) + w1 * bf2f(r1.z) + w2 * bf2f(r2.z) + w3 * bf2f(r3.z);
        a3 += w0 * bf2f(r0.w) + w1 * bf2f(r1.w) + w2 * bf2f(r2.w) + w3 * bf2f(r3.w);
    }
    for (; i < end; ++i) {
        int2 p = perm[i];
        float w = __int_as_float(p.y);
        ushort4 r = ((const ushort4*)(vb + (size_t)p.x * D_IN))[lane];
        a0 += w * bf2f(r.x); a1 += w * bf2f(r.y);
        a2 += w * bf2f(r.z); a3 += w * bf2f(r.w);
    }
    a0 += c0; a1 += c1; a2 += c2; a3 += c3;
    float eps = eps_p[0];
    ushort4 m = ((const ushort4*)(vb + (size_t)node * D_IN))[lane];
    a0 += eps * bf2f(m.x); a1 += eps * bf2f(m.y);
    a2 += eps * bf2f(m.z); a3 += eps * bf2f(m.w);
    ((ushort4*)(aggb + (size_t)node * D_IN))[lane] =
        make_ushort4(f2bf(a0), f2bf(a1), f2bf(a2), f2bf(a3));
}

// ---------------------------------------------------------------------------
// Fused MLP, 64-row tile, reg-pipelined K-loops (unchanged from R6: 59.4us).
// ---------------------------------------------------------------------------
#define HS_IDX(row, col) ((row) * 512 + ((col) ^ (((row) & 7) << 3)))
#define AT_IDX(row, col) ((row) * 256 + ((col) ^ (((row) & 7) << 3)))

__global__ __launch_bounds__(256, 2) void mlp_kernel(
    const ushort* __restrict__ A, const ushort* __restrict__ w1p,
    const ushort* __restrict__ w2p,
    const float* __restrict__ b1, const float* __restrict__ g1, const float* __restrict__ be1,
    const float* __restrict__ b2, const float* __restrict__ g2, const float* __restrict__ be2,
    float* __restrict__ out, int N) {
    __shared__ ushort hs[32768];      // 64 KB
    __shared__ float redf[640];

    int t = threadIdx.x;
    int w = t >> 6, lane = t & 63;
    int row0 = blockIdx.x * 64;
    int fr = lane & 15, q = lane >> 4, kb = q * 8;

    // ---- stage A-tile once: 8 coalesced 1KB loads/wave, source-swizzled ----
    #pragma unroll
    for (int j = 0; j < 8; ++j) {
        int p = (w * 8 + j) * 64 + lane;
        int row = p >> 5, cbs = p & 31;
        int colblk = cbs ^ (row & 7);
        int ar = row0 + row; if (ar > N - 1) ar = N - 1;
        const ushort* gp = A + (size_t)ar * D_IN + colblk * 8;
        __builtin_amdgcn_global_load_lds(
            (const __attribute__((address_space(1))) void*)gp,
            (__attribute__((address_space(3))) void*)(&hs[(w * 8 + j) * 512]),
            16, 0, 0);
    }

    bf16x8 bfb[2][8];
    #pragma unroll
    for (int c = 0; c < 8; ++c)
        bfb[0][c] = *(const bf16x8*)(w1p + (size_t)((w * 8 + c) * 64 + lane) * 8);

    __syncthreads();

    f32x4 acc[4][8];
    #pragma unroll
    for (int m = 0; m < 4; ++m)
        #pragma unroll
        for (int c = 0; c < 8; ++c) {
            f32x4 z = {0.f, 0.f, 0.f, 0.f};
            acc[m][c] = z;
        }

    #pragma unroll
    for (int ks = 0; ks < 8; ++ks) {
        const int cur = ks & 1, nxt = cur ^ 1;
        if (ks < 7) {
            #pragma unroll
            for (int c = 0; c < 8; ++c)
                bfb[nxt][c] = *(const bf16x8*)(w1p +
                    (size_t)(((ks + 1) * 32 + w * 8 + c) * 64 + lane) * 8);
        }
        bf16x8 af[4];
        #pragma unroll
        for (int m = 0; m < 4; ++m)
            af[m] = *(const bf16x8*)&hs[AT_IDX(m * 16 + fr, ks * 32 + kb)];
        #pragma unroll
        for (int m = 0; m < 4; ++m)
            #pragma unroll
            for (int c = 0; c < 8; ++c)
                acc[m][c] = __builtin_amdgcn_mfma_f32_16x16x32_bf16(af[m], bfb[cur][c], acc[m][c], 0, 0, 0);
    }

    {
        float bi[8], gg[8], bb[8];
        #pragma unroll
        for (int c = 0; c < 8; ++c) {
            int col = w * 128 + c * 16 + fr;
            bi[c] = b1[col]; gg[c] = g1[col]; bb[c] = be1[col];
        }
        #pragma unroll
        for (int m = 0; m < 4; ++m) {
            #pragma unroll
            for (int r = 0; r < 4; ++r) {
                float s = 0.f, sq = 0.f;
                #pragma unroll
                for (int c = 0; c < 8; ++c) {
                    float x = acc[m][c][r] + bi[c];
                    acc[m][c][r] = x;
                    s += x; sq += x * x;
                }
                #pragma unroll
                for (int o = 1; o < 16; o <<= 1) {
                    s  += __shfl_xor(s, o, 64);
                    sq += __shfl_xor(sq, o, 64);
                }
                if (fr == 0) {
                    int row = m * 16 + q * 4 + r;
                    redf[row * 4 + w]       = s;
                    redf[256 + row * 4 + w] = sq;
                }
            }
        }
        __syncthreads();
        if (t < 64) {
            float s  = redf[t * 4 + 0] + redf[t * 4 + 1] + redf[t * 4 + 2] + redf[t * 4 + 3];
            float sq = redf[256 + t * 4 + 0] + redf[256 + t * 4 + 1] +
                       redf[256 + t * 4 + 2] + redf[256 + t * 4 + 3];
            float mu = s / (float)D_HID;
            float var = sq / (float)D_HID - mu * mu;
            redf[512 + t] = mu;
            redf[576 + t] = rsqrtf(var + LN_EPS);
        }
        __syncthreads();
        #pragma unroll
        for (int m = 0; m < 4; ++m) {
            #pragma unroll
            for (int r = 0; r < 4; ++r) {
                int row = m * 16 + q * 4 + r;
                float mu = redf[512 + row], rs = redf[576 + row];
                #pragma unroll
                for (int c = 0; c < 8; ++c) {
                    int col = w * 128 + c * 16 + fr;
                    float y = (acc[m][c][r] - mu) * rs * gg[c] + bb[c];
                    hs[HS_IDX(row, col)] = f2bf(fmaxf(y, 0.f));
                }
            }
        }
    }

    bf16x8 bf2b[2][4][2];
    #pragma unroll
    for (int c = 0; c < 4; ++c)
        #pragma unroll
        for (int h = 0; h < 2; ++h)
            bf2b[0][c][h] = *(const bf16x8*)(w2p +
                (size_t)(((0 + h) * 16 + w * 4 + c) * 64 + lane) * 8);

    __syncthreads();

    f32x4 acc2[4][4];
    #pragma unroll
    for (int m = 0; m < 4; ++m)
        #pragma unroll
        for (int c = 0; c < 4; ++c) {
            f32x4 z = {0.f, 0.f, 0.f, 0.f};
            acc2[m][c] = z;
        }

    #pragma unroll
    for (int s2 = 0; s2 < 8; ++s2) {
        const int cur = s2 & 1, nxt = cur ^ 1;
        if (s2 < 7) {
            #pragma unroll
            for (int c = 0; c < 4; ++c)
                #pragma unroll
                for (int h = 0; h < 2; ++h)
                    bf2b[nxt][c][h] = *(const bf16x8*)(w2p +
                        (size_t)(((2 * (s2 + 1) + h) * 16 + w * 4 + c) * 64 + lane) * 8);
        }
        bf16x8 af2[4][2];
        #pragma unroll
        for (int m = 0; m < 4; ++m)
            #pragma unroll
            for (int h = 0; h < 2; ++h)
                af2[m][h] = *(const bf16x8*)&hs[HS_IDX(m * 16 + fr, s2 * 64 + h * 32 + kb)];
        #pragma unroll
        for (int m = 0; m < 4; ++m)
            #pragma unroll
            for (int c = 0; c < 4; ++c)
                #pragma unroll
                for (int h = 0; h < 2; ++h)
                    acc2[m][c] = __builtin_amdgcn_mfma_f32_16x16x32_bf16(af2[m][h], bf2b[cur][c][h], acc2[m][c], 0, 0, 0);
    }

    {
        float bi[4], gg[4], bb[4];
        #pragma unroll
        for (int c = 0; c < 4; ++c) {
            int col = w * 64 + c * 16 + fr;
            bi[c] = b2[col]; gg[c] = g2[col]; bb[c] = be2[col];
        }
        #pragma unroll
        for (int m = 0; m < 4; ++m) {
            #pragma unroll
            for (int r = 0; r < 4; ++r) {
                float s = 0.f, sq = 0.f;
                #pragma unroll
                for (int c = 0; c < 4; ++c) {
                    float x = acc2[m][c][r] + bi[c];
                    acc2[m][c][r] = x;
                    s += x; sq += x * x;
                }
                #pragma unroll
                for (int o = 1; o < 16; o <<= 1) {
                    s  += __shfl_xor(s, o, 64);
                    sq += __shfl_xor(sq, o, 64);
                }
                if (fr == 0) {
                    int row = m * 16 + q * 4 + r;
                    redf[row * 4 + w]       = s;
                    redf[256 + row * 4 + w] = sq;
                }
            }
        }
        __syncthreads();
        if (t < 64) {
            float s  = redf[t * 4 + 0] + redf[t * 4 + 1] + redf[t * 4 + 2] + redf[t * 4 + 3];
            float sq = redf[256 + t * 4 + 0] + redf[256 + t * 4 + 1] +
                       redf[256 + t * 4 + 2] + redf[256 + t * 4 + 3];
            float mu = s / (float)D_OUT;
            float var = sq / (float)D_OUT - mu * mu;
            redf[512 + t] = mu;
            redf[576 + t] = rsqrtf(var + LN_EPS);
        }
        __syncthreads();
        #pragma unroll
        for (int m = 0; m < 4; ++m) {
            #pragma unroll
            for (int r = 0; r < 4; ++r) {
                int row = m * 16 + q * 4 + r;
                int grow = row0 + row;
                if (grow >= N) continue;
                float mu = redf[512 + row], rs = redf[576 + row];
                #pragma unroll
                for (int c = 0; c < 4; ++c) {
                    int col = w * 64 + c * 16 + fr;
                    float y = (acc2[m][c][r] - mu) * rs * gg[c] + bb[c];
                    out[(size_t)grow * D_OUT + col] = fmaxf(y, 0.f);
                }
            }
        }
    }
}

// ---------------------------------------------------------------------------
extern "C" void kernel_launch(void* const* d_in, const int* in_sizes, int n_in,
                              void* d_out, int out_size, void* d_ws, size_t ws_size,
                              hipStream_t stream) {
    const float* v     = (const float*)d_in[0];
    const float* ew    = (const float*)d_in[1];
    const float* eps   = (const float*)d_in[2];
    const float* w1    = (const float*)d_in[3];
    const float* b1    = (const float*)d_in[4];
    const float* g1    = (const float*)d_in[5];
    const float* beta1 = (const float*)d_in[6];
    const float* w2    = (const float*)d_in[7];
    const float* b2    = (const float*)d_in[8];
    const float* g2    = (const float*)d_in[9];
    const float* beta2 = (const float*)d_in[10];
    const int*   src   = (const int*)d_in[11];
    const int*   dst   = (const int*)d_in[12];

    int N = in_sizes[0] / D_IN;     // 50000
    int E = in_sizes[1];            // 800000

    float* out = (float*)d_out;

    // workspace layout (256B-aligned chunks)
    char* ws = (char*)d_ws;
    size_t off = 0;
    ushort* vb   = (ushort*)(ws + off); off += (size_t)N * D_IN * 2;            // 25.6 MB
    ushort* aggb = (ushort*)(ws + off); off += (size_t)N * D_IN * 2;            // 25.6 MB
    ushort* w1p  = (ushort*)(ws + off); off += (size_t)D_HID * D_IN * 2;        // 256 KB
    ushort* w2p  = (ushort*)(ws + off); off += (size_t)D_OUT * D_HID * 2;       // 256 KB
    int* offs     = (int*)(ws + off); off += (size_t)(N + 256) * 4;
    int* cnt      = (int*)(ws + off); off += (size_t)(N + 256) * 4;             // zeroed
    int* bar      = (int*)(ws + off); off += 64 * 4;                            // zeroed
    int* bsum     = (int*)(ws + off); off += 1024;
    int* rank     = (int*)(ws + off); off += (size_t)E * 4;                     // 3.2 MB
    int2* perm    = (int2*)(ws + off); off += (size_t)E * 8;                    // 6.4 MB

    int n4v = N * (D_IN / 4);
    int nch = (N + 255) / 256;       // 196 scan chunks (<= 256)

    // 0) zero histogram + barrier counters (cnt and bar are contiguous)
    hipMemsetAsync(cnt, 0, ((size_t)(N + 256) + 64) * 4, stream);

    // 1) mega: casts + hist/rank | chunk-scan | base-scan | fill
    mega_kernel<<<NBLK, 256, 0, stream>>>(v, w1, w2, vb, w1p, w2p,
                                          src, dst, ew,
                                          rank, cnt, bar, offs, bsum, perm,
                                          N, E, n4v, nch);

    // 2) aggregate (bf16 gather), high-TLP standalone
    aggregate_kernel<<<(N + 3) / 4, 256, 0, stream>>>(vb, eps, offs, bsum, perm, aggb, N);

    // 3) fused MLP
    int mblocks = (N + 63) / 64;
    mlp_kernel<<<mblocks, 256, 0, stream>>>(aggb, w1p, w2p,
                                            b1, g1, beta1, b2, g2, beta2, out, N);
}

// Round 9
// 368.514 us; speedup vs baseline: 3.0299x; 2.3549x over previous
//
#include <hip/hip_runtime.h>

#define D_IN 256
#define D_HID 512
#define D_OUT 256
#define LN_EPS 1e-5f
#define SCB 1024

typedef __attribute__((ext_vector_type(8))) short bf16x8;
typedef __attribute__((ext_vector_type(4))) float f32x4;

__device__ __forceinline__ ushort f2bf(float x) {
    union { float f; unsigned u; } c; c.f = x;
    unsigned r = c.u + 0x7FFFu + ((c.u >> 16) & 1u);   // round-to-nearest-even
    return (ushort)(r >> 16);
}
__device__ __forceinline__ float bf2f(unsigned b) {
    union { unsigned u; float f; } c; c.u = b << 16;
    return c.f;
}

// ---------------------------------------------------------------------------
// prep: cvt v->bf16 | cvt w1,w2->bf16 PACKED in MFMA-fragment order |
//       edge hist+rank (cnt pre-zeroed by hipMemsetAsync)
// ---------------------------------------------------------------------------
__global__ void prep_kernel(const float* __restrict__ v, const float* __restrict__ w1,
                            const float* __restrict__ w2, ushort* __restrict__ vb,
                            ushort* __restrict__ w1p, ushort* __restrict__ w2p,
                            const int* __restrict__ dst, int* __restrict__ rank,
                            int* __restrict__ cnt, int n4v, int E,
                            int bv, int bw) {
    int b = blockIdx.x, t = threadIdx.x;
    if (b < bv) {
        int i = b * 256 + t;
        if (i < n4v) {
            float4 x = ((const float4*)v)[i];
            ((ushort4*)vb)[i] = make_ushort4(f2bf(x.x), f2bf(x.y), f2bf(x.z), f2bf(x.w));
        }
    } else if (b < bv + bw) {
        int j = (b - bv) * 256 + t;     // 0..65535 float4s (w1: first 32768)
        if (j < 32768) {                // w1: [512][256] fp32
            int f = j * 4;
            int row = f >> 8, col = f & 255;
            float4 x = ((const float4*)w1)[j];
            int rb = row >> 4, fr = row & 15;
            int kb32 = col >> 5, q = (col & 31) >> 3, e = col & 7;
            int chunk = (kb32 * 32 + rb) * 64 + q * 16 + fr;
            *(ushort4*)(w1p + chunk * 8 + e) =
                make_ushort4(f2bf(x.x), f2bf(x.y), f2bf(x.z), f2bf(x.w));
        } else {                        // w2: [256][512] fp32
            int k = j - 32768;
            int f = k * 4;
            int row = f >> 9, col = f & 511;
            float4 x = ((const float4*)w2)[k];
            int rb = row >> 4, fr = row & 15;
            int kb32 = col >> 5, q = (col & 31) >> 3, e = col & 7;
            int chunk = (kb32 * 16 + rb) * 64 + q * 16 + fr;
            *(ushort4*)(w2p + chunk * 8 + e) =
                make_ushort4(f2bf(x.x), f2bf(x.y), f2bf(x.z), f2bf(x.w));
        }
    } else {
        int e = (b - bv - bw) * 256 + t;
        if (e < E) rank[e] = atomicAdd(&cnt[dst[e]], 1);
    }
}

// ---------------------------------------------------------------------------
// single-block scan: offs = exclusive_scan(cnt), offs[N] = E  (one launch,
// replaces scan1+scan3). 1024 threads x 49-element serial chunks, then
// shfl wave-scan + cross-wave LDS scan. ~200KB through one CU ≈ 3-4us.
// ---------------------------------------------------------------------------
__global__ __launch_bounds__(SCB) void scan_kernel(const int* __restrict__ cnt,
                                                   int* __restrict__ offs,
                                                   int N, int E) {
    __shared__ int wsum[SCB / 64];
    int t = threadIdx.x;
    int c = (N + SCB - 1) / SCB;                  // 49
    int lo = t * c, hi = lo + c; if (hi > N) hi = N;
    int sum = 0;
    for (int i = lo; i < hi; ++i) sum += cnt[i];
    int lane = t & 63, wv = t >> 6;
    int incl = sum;
    #pragma unroll
    for (int o = 1; o < 64; o <<= 1) {
        int u = __shfl_up(incl, o, 64);
        if (lane >= o) incl += u;
    }
    if (lane == 63) wsum[wv] = incl;
    __syncthreads();
    if (t < SCB / 64) {                           // 16 wave sums, scan in wave 0
        int x = wsum[t];
        #pragma unroll
        for (int o = 1; o < SCB / 64; o <<= 1) {
            int u = __shfl_up(x, o, 64);
            if (t >= o) x += u;
        }
        wsum[t] = x;                              // inclusive
    }
    __syncthreads();
    int run = (wv > 0 ? wsum[wv - 1] : 0) + (incl - sum);   // exclusive prefix
    for (int i = lo; i < hi; ++i) { int x = cnt[i]; offs[i] = run; run += x; }
    if (t == 0) offs[N] = E;
}

// counting-sort fill, NO atomics: slot = offs[dst] + rank (unique by constr.)
__global__ void fill_kernel(const int* __restrict__ src, const int* __restrict__ dst,
                            const float* __restrict__ ew, const int* __restrict__ rank,
                            const int* __restrict__ offs,
                            int2* __restrict__ perm, int E) {
    int e = blockIdx.x * 256 + threadIdx.x;
    if (e >= E) return;
    int p = offs[dst[e]] + rank[e];
    perm[p] = make_int2(src[e], __float_as_int(ew[e]));
}

// ---------------------------------------------------------------------------
// agg_bf16[n] = bf16( eps*vb[n] + sum_{e:dst=n} w_e * vb[src_e] )
// one wave/node, 12.5k blocks for TLP (R6: 59.6us, occ 60%).
// ---------------------------------------------------------------------------
__global__ __launch_bounds__(256) void aggregate_kernel(
    const ushort* __restrict__ vb, const float* __restrict__ eps_p,
    const int* __restrict__ offs, const int2* __restrict__ perm,
    ushort* __restrict__ aggb, int N) {
    int node = blockIdx.x * 4 + (threadIdx.x >> 6);
    if (node >= N) return;
    int lane = threadIdx.x & 63;
    int beg = offs[node], end = offs[node + 1];
    float a0 = 0.f, a1 = 0.f, a2 = 0.f, a3 = 0.f;
    float c0 = 0.f, c1 = 0.f, c2 = 0.f, c3 = 0.f;

    int i = beg;
    for (; i + 8 <= end; i += 8) {
        int2 p0 = perm[i + 0], p1 = perm[i + 1], p2 = perm[i + 2], p3 = perm[i + 3];
        int2 p4 = perm[i + 4], p5 = perm[i + 5], p6 = perm[i + 6], p7 = perm[i + 7];
        float w0 = __int_as_float(p0.y), w1 = __int_as_float(p1.y);
        float w2 = __int_as_float(p2.y), w3 = __int_as_float(p3.y);
        float w4 = __int_as_float(p4.y), w5 = __int_as_float(p5.y);
        float w6 = __int_as_float(p6.y), w7 = __int_as_float(p7.y);
        ushort4 r0 = ((const ushort4*)(vb + (size_t)p0.x * D_IN))[lane];
        ushort4 r1 = ((const ushort4*)(vb + (size_t)p1.x * D_IN))[lane];
        ushort4 r2 = ((const ushort4*)(vb + (size_t)p2.x * D_IN))[lane];
        ushort4 r3 = ((const ushort4*)(vb + (size_t)p3.x * D_IN))[lane];
        ushort4 r4 = ((const ushort4*)(vb + (size_t)p4.x * D_IN))[lane];
        ushort4 r5 = ((const ushort4*)(vb + (size_t)p5.x * D_IN))[lane];
        ushort4 r6 = ((const ushort4*)(vb + (size_t)p6.x * D_IN))[lane];
        ushort4 r7 = ((const ushort4*)(vb + (size_t)p7.x * D_IN))[lane];
        a0 += w0 * bf2f(r0.x) + w1 * bf2f(r1.x) + w2 * bf2f(r2.x) + w3 * bf2f(r3.x);
        a1 += w0 * bf2f(r0.y) + w1 * bf2f(r1.y) + w2 * bf2f(r2.y) + w3 * bf2f(r3.y);
        a2 += w0 * bf2f(r0.z) + w1 * bf2f(r1.z) + w2 * bf2f(r2.z) + w3 * bf2f(r3.z);
        a3 += w0 * bf2f(r0.w) + w1 * bf2f(r1.w) + w2 * bf2f(r2.w) + w3 * bf2f(r3.w);
        c0 += w4 * bf2f(r4.x) + w5 * bf2f(r5.x) + w6 * bf2f(r6.x) + w7 * bf2f(r7.x);
        c1 += w4 * bf2f(r4.y) + w5 * bf2f(r5.y) + w6 * bf2f(r6.y) + w7 * bf2f(r7.y);
        c2 += w4 * bf2f(r4.z) + w5 * bf2f(r5.z) + w6 * bf2f(r6.z) + w7 * bf2f(r7.z);
        c3 += w4 * bf2f(r4.w) + w5 * bf2f(r5.w) + w6 * bf2f(r6.w) + w7 * bf2f(r7.w);
    }
    for (; i + 4 <= end; i += 4) {
        int2 p0 = perm[i + 0], p1 = perm[i + 1], p2 = perm[i + 2], p3 = perm[i + 3];
        float w0 = __int_as_float(p0.y), w1 = __int_as_float(p1.y);
        float w2 = __int_as_float(p2.y), w3 = __int_as_float(p3.y);
        ushort4 r0 = ((const ushort4*)(vb + (size_t)p0.x * D_IN))[lane];
        ushort4 r1 = ((const ushort4*)(vb + (size_t)p1.x * D_IN))[lane];
        ushort4 r2 = ((const ushort4*)(vb + (size_t)p2.x * D_IN))[lane];
        ushort4 r3 = ((const ushort4*)(vb + (size_t)p3.x * D_IN))[lane];
        a0 += w0 * bf2f(r0.x) + w1 * bf2f(r1.x) + w2 * bf2f(r2.x) + w3 * bf2f(r3.x);
        a1 += w0 * bf2f(r0.y) + w1 * bf2f(r1.y) + w2 * bf2f(r2.y) + w3 * bf2f(r3.y);
        a2 += w0 * bf2f(r0.z) + w1 * bf2f(r1.z) + w2 * bf2f(r2.z) + w3 * bf2f(r3.z);
        a3 += w0 * bf2f(r0.w) + w1 * bf2f(r1.w) + w2 * bf2f(r2.w) + w3 * bf2f(r3.w);
    }
    for (; i < end; ++i) {
        int2 p = perm[i];
        float w = __int_as_float(p.y);
        ushort4 r = ((const ushort4*)(vb + (size_t)p.x * D_IN))[lane];
        a0 += w * bf2f(r.x); a1 += w * bf2f(r.y);
        a2 += w * bf2f(r.z); a3 += w * bf2f(r.w);
    }
    a0 += c0; a1 += c1; a2 += c2; a3 += c3;
    float eps = eps_p[0];
    ushort4 m = ((const ushort4*)(vb + (size_t)node * D_IN))[lane];
    a0 += eps * bf2f(m.x); a1 += eps * bf2f(m.y);
    a2 += eps * bf2f(m.z); a3 += eps * bf2f(m.w);
    ((ushort4*)(aggb + (size_t)node * D_IN))[lane] =
        make_ushort4(f2bf(a0), f2bf(a1), f2bf(a2), f2bf(a3));
}

// ---------------------------------------------------------------------------
// Fused MLP, 64-row tile, reg-pipelined K-loops (R6-proven: 59.4us).
// ---------------------------------------------------------------------------
#define HS_IDX(row, col) ((row) * 512 + ((col) ^ (((row) & 7) << 3)))
#define AT_IDX(row, col) ((row) * 256 + ((col) ^ (((row) & 7) << 3)))

__global__ __launch_bounds__(256, 2) void mlp_kernel(
    const ushort* __restrict__ A, const ushort* __restrict__ w1p,
    const ushort* __restrict__ w2p,
    const float* __restrict__ b1, const float* __restrict__ g1, const float* __restrict__ be1,
    const float* __restrict__ b2, const float* __restrict__ g2, const float* __restrict__ be2,
    float* __restrict__ out, int N) {
    __shared__ ushort hs[32768];      // 64 KB
    __shared__ float redf[640];

    int t = threadIdx.x;
    int w = t >> 6, lane = t & 63;
    int row0 = blockIdx.x * 64;
    int fr = lane & 15, q = lane >> 4, kb = q * 8;

    // ---- stage A-tile once: 8 coalesced 1KB loads/wave, source-swizzled ----
    #pragma unroll
    for (int j = 0; j < 8; ++j) {
        int p = (w * 8 + j) * 64 + lane;
        int row = p >> 5, cbs = p & 31;
        int colblk = cbs ^ (row & 7);
        int ar = row0 + row; if (ar > N - 1) ar = N - 1;
        const ushort* gp = A + (size_t)ar * D_IN + colblk * 8;
        __builtin_amdgcn_global_load_lds(
            (const __attribute__((address_space(1))) void*)gp,
            (__attribute__((address_space(3))) void*)(&hs[(w * 8 + j) * 512]),
            16, 0, 0);
    }

    bf16x8 bfb[2][8];
    #pragma unroll
    for (int c = 0; c < 8; ++c)
        bfb[0][c] = *(const bf16x8*)(w1p + (size_t)((w * 8 + c) * 64 + lane) * 8);

    __syncthreads();

    f32x4 acc[4][8];
    #pragma unroll
    for (int m = 0; m < 4; ++m)
        #pragma unroll
        for (int c = 0; c < 8; ++c) {
            f32x4 z = {0.f, 0.f, 0.f, 0.f};
            acc[m][c] = z;
        }

    #pragma unroll
    for (int ks = 0; ks < 8; ++ks) {
        const int cur = ks & 1, nxt = cur ^ 1;
        if (ks < 7) {
            #pragma unroll
            for (int c = 0; c < 8; ++c)
                bfb[nxt][c] = *(const bf16x8*)(w1p +
                    (size_t)(((ks + 1) * 32 + w * 8 + c) * 64 + lane) * 8);
        }
        bf16x8 af[4];
        #pragma unroll
        for (int m = 0; m < 4; ++m)
            af[m] = *(const bf16x8*)&hs[AT_IDX(m * 16 + fr, ks * 32 + kb)];
        #pragma unroll
        for (int m = 0; m < 4; ++m)
            #pragma unroll
            for (int c = 0; c < 8; ++c)
                acc[m][c] = __builtin_amdgcn_mfma_f32_16x16x32_bf16(af[m], bfb[cur][c], acc[m][c], 0, 0, 0);
    }

    {
        float bi[8], gg[8], bb[8];
        #pragma unroll
        for (int c = 0; c < 8; ++c) {
            int col = w * 128 + c * 16 + fr;
            bi[c] = b1[col]; gg[c] = g1[col]; bb[c] = be1[col];
        }
        #pragma unroll
        for (int m = 0; m < 4; ++m) {
            #pragma unroll
            for (int r = 0; r < 4; ++r) {
                float s = 0.f, sq = 0.f;
                #pragma unroll
                for (int c = 0; c < 8; ++c) {
                    float x = acc[m][c][r] + bi[c];
                    acc[m][c][r] = x;
                    s += x; sq += x * x;
                }
                #pragma unroll
                for (int o = 1; o < 16; o <<= 1) {
                    s  += __shfl_xor(s, o, 64);
                    sq += __shfl_xor(sq, o, 64);
                }
                if (fr == 0) {
                    int row = m * 16 + q * 4 + r;
                    redf[row * 4 + w]       = s;
                    redf[256 + row * 4 + w] = sq;
                }
            }
        }
        __syncthreads();
        if (t < 64) {
            float s  = redf[t * 4 + 0] + redf[t * 4 + 1] + redf[t * 4 + 2] + redf[t * 4 + 3];
            float sq = redf[256 + t * 4 + 0] + redf[256 + t * 4 + 1] +
                       redf[256 + t * 4 + 2] + redf[256 + t * 4 + 3];
            float mu = s / (float)D_HID;
            float var = sq / (float)D_HID - mu * mu;
            redf[512 + t] = mu;
            redf[576 + t] = rsqrtf(var + LN_EPS);
        }
        __syncthreads();
        #pragma unroll
        for (int m = 0; m < 4; ++m) {
            #pragma unroll
            for (int r = 0; r < 4; ++r) {
                int row = m * 16 + q * 4 + r;
                float mu = redf[512 + row], rs = redf[576 + row];
                #pragma unroll
                for (int c = 0; c < 8; ++c) {
                    int col = w * 128 + c * 16 + fr;
                    float y = (acc[m][c][r] - mu) * rs * gg[c] + bb[c];
                    hs[HS_IDX(row, col)] = f2bf(fmaxf(y, 0.f));
                }
            }
        }
    }

    bf16x8 bf2b[2][4][2];
    #pragma unroll
    for (int c = 0; c < 4; ++c)
        #pragma unroll
        for (int h = 0; h < 2; ++h)
            bf2b[0][c][h] = *(const bf16x8*)(w2p +
                (size_t)(((0 + h) * 16 + w * 4 + c) * 64 + lane) * 8);

    __syncthreads();

    f32x4 acc2[4][4];
    #pragma unroll
    for (int m = 0; m < 4; ++m)
        #pragma unroll
        for (int c = 0; c < 4; ++c) {
            f32x4 z = {0.f, 0.f, 0.f, 0.f};
            acc2[m][c] = z;
        }

    #pragma unroll
    for (int s2 = 0; s2 < 8; ++s2) {
        const int cur = s2 & 1, nxt = cur ^ 1;
        if (s2 < 7) {
            #pragma unroll
            for (int c = 0; c < 4; ++c)
                #pragma unroll
                for (int h = 0; h < 2; ++h)
                    bf2b[nxt][c][h] = *(const bf16x8*)(w2p +
                        (size_t)(((2 * (s2 + 1) + h) * 16 + w * 4 + c) * 64 + lane) * 8);
        }
        bf16x8 af2[4][2];
        #pragma unroll
        for (int m = 0; m < 4; ++m)
            #pragma unroll
            for (int h = 0; h < 2; ++h)
                af2[m][h] = *(const bf16x8*)&hs[HS_IDX(m * 16 + fr, s2 * 64 + h * 32 + kb)];
        #pragma unroll
        for (int m = 0; m < 4; ++m)
            #pragma unroll
            for (int c = 0; c < 4; ++c)
                #pragma unroll
                for (int h = 0; h < 2; ++h)
                    acc2[m][c] = __builtin_amdgcn_mfma_f32_16x16x32_bf16(af2[m][h], bf2b[cur][c][h], acc2[m][c], 0, 0, 0);
    }

    {
        float bi[4], gg[4], bb[4];
        #pragma unroll
        for (int c = 0; c < 4; ++c) {
            int col = w * 64 + c * 16 + fr;
            bi[c] = b2[col]; gg[c] = g2[col]; bb[c] = be2[col];
        }
        #pragma unroll
        for (int m = 0; m < 4; ++m) {
            #pragma unroll
            for (int r = 0; r < 4; ++r) {
                float s = 0.f, sq = 0.f;
                #pragma unroll
                for (int c = 0; c < 4; ++c) {
                    float x = acc2[m][c][r] + bi[c];
                    acc2[m][c][r] = x;
                    s += x; sq += x * x;
                }
                #pragma unroll
                for (int o = 1; o < 16; o <<= 1) {
                    s  += __shfl_xor(s, o, 64);
                    sq += __shfl_xor(sq, o, 64);
                }
                if (fr == 0) {
                    int row = m * 16 + q * 4 + r;
                    redf[row * 4 + w]       = s;
                    redf[256 + row * 4 + w] = sq;
                }
            }
        }
        __syncthreads();
        if (t < 64) {
            float s  = redf[t * 4 + 0] + redf[t * 4 + 1] + redf[t * 4 + 2] + redf[t * 4 + 3];
            float sq = redf[256 + t * 4 + 0] + redf[256 + t * 4 + 1] +
                       redf[256 + t * 4 + 2] + redf[256 + t * 4 + 3];
            float mu = s / (float)D_OUT;
            float var = sq / (float)D_OUT - mu * mu;
            redf[512 + t] = mu;
            redf[576 + t] = rsqrtf(var + LN_EPS);
        }
        __syncthreads();
        #pragma unroll
        for (int m = 0; m < 4; ++m) {
            #pragma unroll
            for (int r = 0; r < 4; ++r) {
                int row = m * 16 + q * 4 + r;
                int grow = row0 + row;
                if (grow >= N) continue;
                float mu = redf[512 + row], rs = redf[576 + row];
                #pragma unroll
                for (int c = 0; c < 4; ++c) {
                    int col = w * 64 + c * 16 + fr;
                    float y = (acc2[m][c][r] - mu) * rs * gg[c] + bb[c];
                    out[(size_t)grow * D_OUT + col] = fmaxf(y, 0.f);
                }
            }
        }
    }
}

// ---------------------------------------------------------------------------
extern "C" void kernel_launch(void* const* d_in, const int* in_sizes, int n_in,
                              void* d_out, int out_size, void* d_ws, size_t ws_size,
                              hipStream_t stream) {
    const float* v     = (const float*)d_in[0];
    const float* ew    = (const float*)d_in[1];
    const float* eps   = (const float*)d_in[2];
    const float* w1    = (const float*)d_in[3];
    const float* b1    = (const float*)d_in[4];
    const float* g1    = (const float*)d_in[5];
    const float* beta1 = (const float*)d_in[6];
    const float* w2    = (const float*)d_in[7];
    const float* b2    = (const float*)d_in[8];
    const float* g2    = (const float*)d_in[9];
    const float* beta2 = (const float*)d_in[10];
    const int*   src   = (const int*)d_in[11];
    const int*   dst   = (const int*)d_in[12];

    int N = in_sizes[0] / D_IN;     // 50000
    int E = in_sizes[1];            // 800000

    float* out = (float*)d_out;

    // workspace layout (256B-aligned chunks)
    char* ws = (char*)d_ws;
    size_t off = 0;
    ushort* vb   = (ushort*)(ws + off); off += (size_t)N * D_IN * 2;            // 25.6 MB
    ushort* aggb = (ushort*)(ws + off); off += (size_t)N * D_IN * 2;            // 25.6 MB
    ushort* w1p  = (ushort*)(ws + off); off += (size_t)D_HID * D_IN * 2;        // 256 KB
    ushort* w2p  = (ushort*)(ws + off); off += (size_t)D_OUT * D_HID * 2;       // 256 KB
    int* offs     = (int*)(ws + off); off += (size_t)(N + 256) * 4;
    int* cnt      = (int*)(ws + off); off += (size_t)(N + 256) * 4;             // zeroed
    int* rank     = (int*)(ws + off); off += (size_t)E * 4;                     // 3.2 MB
    int2* perm    = (int2*)(ws + off); off += (size_t)E * 8;                    // 6.4 MB

    int n4v = N * (D_IN / 4);
    int bv = (n4v + 255) / 256;
    int bw = 256;                     // 65536 float4s of weights
    int be = (E + 255) / 256;

    // 0) zero the histogram
    hipMemsetAsync(cnt, 0, (size_t)N * 4, stream);

    // 1) prep: casts + packed weights + edge hist/rank
    prep_kernel<<<bv + bw + be, 256, 0, stream>>>(v, w1, w2, vb, w1p, w2p,
                                                  dst, rank, cnt, n4v, E, bv, bw);

    // 2) single-launch scan: offs = exscan(cnt), offs[N]=E
    scan_kernel<<<1, SCB, 0, stream>>>(cnt, offs, N, E);

    // 3) counting-sort fill (no atomics)
    fill_kernel<<<be, 256, 0, stream>>>(src, dst, ew, rank, offs, perm, E);

    // 4) aggregate (bf16 gather), high-TLP standalone
    aggregate_kernel<<<(N + 3) / 4, 256, 0, stream>>>(vb, eps, offs, perm, aggb, N);

    // 5) fused MLP
    int mblocks = (N + 63) / 64;
    mlp_kernel<<<mblocks, 256, 0, stream>>>(aggb, w1p, w2p,
                                            b1, g1, beta1, b2, g2, beta2, out, N);
}

// Round 10
// 304.609 us; speedup vs baseline: 3.6656x; 1.2098x over previous
//
#include <hip/hip_runtime.h>

#define D_IN 256
#define D_HID 512
#define D_OUT 256
#define LN_EPS 1e-5f
#define SCAN_B 512

typedef __attribute__((ext_vector_type(8))) short bf16x8;
typedef __attribute__((ext_vector_type(4))) float f32x4;

__device__ __forceinline__ ushort f2bf(float x) {
    union { float f; unsigned u; } c; c.f = x;
    unsigned r = c.u + 0x7FFFu + ((c.u >> 16) & 1u);   // round-to-nearest-even
    return (ushort)(r >> 16);
}
__device__ __forceinline__ float bf2f(unsigned b) {
    union { unsigned u; float f; } c; c.u = b << 16;
    return c.f;
}

// ---------------------------------------------------------------------------
// prep: cvt v->bf16 | cvt w1,w2->bf16 PACKED in MFMA-fragment order |
//       edge hist+rank (cnt pre-zeroed by hipMemsetAsync)
// ---------------------------------------------------------------------------
__global__ void prep_kernel(const float* __restrict__ v, const float* __restrict__ w1,
                            const float* __restrict__ w2, ushort* __restrict__ vb,
                            ushort* __restrict__ w1p, ushort* __restrict__ w2p,
                            const int* __restrict__ dst, int* __restrict__ rank,
                            int* __restrict__ cnt, int n4v, int E,
                            int bv, int bw) {
    int b = blockIdx.x, t = threadIdx.x;
    if (b < bv) {
        int i = b * 256 + t;
        if (i < n4v) {
            float4 x = ((const float4*)v)[i];
            ((ushort4*)vb)[i] = make_ushort4(f2bf(x.x), f2bf(x.y), f2bf(x.z), f2bf(x.w));
        }
    } else if (b < bv + bw) {
        int j = (b - bv) * 256 + t;     // 0..65535 float4s (w1: first 32768)
        if (j < 32768) {                // w1: [512][256] fp32
            int f = j * 4;
            int row = f >> 8, col = f & 255;
            float4 x = ((const float4*)w1)[j];
            int rb = row >> 4, fr = row & 15;
            int kb32 = col >> 5, q = (col & 31) >> 3, e = col & 7;
            int chunk = (kb32 * 32 + rb) * 64 + q * 16 + fr;
            *(ushort4*)(w1p + chunk * 8 + e) =
                make_ushort4(f2bf(x.x), f2bf(x.y), f2bf(x.z), f2bf(x.w));
        } else {                        // w2: [256][512] fp32
            int k = j - 32768;
            int f = k * 4;
            int row = f >> 9, col = f & 511;
            float4 x = ((const float4*)w2)[k];
            int rb = row >> 4, fr = row & 15;
            int kb32 = col >> 5, q = (col & 31) >> 3, e = col & 7;
            int chunk = (kb32 * 16 + rb) * 64 + q * 16 + fr;
            *(ushort4*)(w2p + chunk * 8 + e) =
                make_ushort4(f2bf(x.x), f2bf(x.y), f2bf(x.z), f2bf(x.w));
        }
    } else {
        int e = (b - bv - bw) * 256 + t;
        if (e < E) rank[e] = atomicAdd(&cnt[dst[e]], 1);
    }
}

// ---------------------------------------------------------------------------
// CSR offsets: two-level scan (R6-proven; single-block scan was 77us - R9)
// ---------------------------------------------------------------------------
__global__ __launch_bounds__(SCAN_B) void scan1_kernel(const int* __restrict__ cnt,
                                                       int* __restrict__ offs,
                                                       int* __restrict__ bsum, int n) {
    __shared__ int s[SCAN_B];
    int i = blockIdx.x * SCAN_B + threadIdx.x;
    int x = (i < n) ? cnt[i] : 0;
    s[threadIdx.x] = x;
    __syncthreads();
    for (int o = 1; o < SCAN_B; o <<= 1) {
        int t = (threadIdx.x >= (unsigned)o) ? s[threadIdx.x - o] : 0;
        __syncthreads();
        s[threadIdx.x] += t;
        __syncthreads();
    }
    if (i < n) offs[i] = s[threadIdx.x] - x;
    if (threadIdx.x == SCAN_B - 1) bsum[blockIdx.x] = s[threadIdx.x];
}

__global__ __launch_bounds__(SCAN_B) void scan3_kernel(int* __restrict__ offs,
                                                       const int* __restrict__ bsum,
                                                       int n, int E, int nb) {
    __shared__ int s[SCAN_B];
    int t = threadIdx.x;
    s[t] = (t < nb && t < (int)blockIdx.x) ? bsum[t] : 0;
    __syncthreads();
    for (int o = SCAN_B / 2; o > 0; o >>= 1) {
        if (t < o) s[t] += s[t + o];
        __syncthreads();
    }
    int base = s[0];
    int i = blockIdx.x * SCAN_B + t;
    if (i < n) offs[i] += base;
    if (i == 0) offs[n] = E;
}

// counting-sort fill, NO atomics: slot = offs[dst] + rank (unique by constr.)
__global__ void fill_kernel(const int* __restrict__ src, const int* __restrict__ dst,
                            const float* __restrict__ ew, const int* __restrict__ rank,
                            const int* __restrict__ offs,
                            int2* __restrict__ perm, int E) {
    int e = blockIdx.x * 256 + threadIdx.x;
    if (e >= E) return;
    int p = offs[dst[e]] + rank[e];
    perm[p] = make_int2(src[e], __float_as_int(ew[e]));
}

// ---------------------------------------------------------------------------
// agg_bf16[n] = bf16( eps*vb[n] + sum_{e:dst=n} w_e * vb[src_e] )
// one wave/node, 12.5k blocks for TLP (R6: 59.6us, occ 60%).
// ---------------------------------------------------------------------------
__global__ __launch_bounds__(256) void aggregate_kernel(
    const ushort* __restrict__ vb, const float* __restrict__ eps_p,
    const int* __restrict__ offs, const int2* __restrict__ perm,
    ushort* __restrict__ aggb, int N) {
    int node = blockIdx.x * 4 + (threadIdx.x >> 6);
    if (node >= N) return;
    int lane = threadIdx.x & 63;
    int beg = offs[node], end = offs[node + 1];
    float a0 = 0.f, a1 = 0.f, a2 = 0.f, a3 = 0.f;
    float c0 = 0.f, c1 = 0.f, c2 = 0.f, c3 = 0.f;

    int i = beg;
    for (; i + 8 <= end; i += 8) {
        int2 p0 = perm[i + 0], p1 = perm[i + 1], p2 = perm[i + 2], p3 = perm[i + 3];
        int2 p4 = perm[i + 4], p5 = perm[i + 5], p6 = perm[i + 6], p7 = perm[i + 7];
        float w0 = __int_as_float(p0.y), w1 = __int_as_float(p1.y);
        float w2 = __int_as_float(p2.y), w3 = __int_as_float(p3.y);
        float w4 = __int_as_float(p4.y), w5 = __int_as_float(p5.y);
        float w6 = __int_as_float(p6.y), w7 = __int_as_float(p7.y);
        ushort4 r0 = ((const ushort4*)(vb + (size_t)p0.x * D_IN))[lane];
        ushort4 r1 = ((const ushort4*)(vb + (size_t)p1.x * D_IN))[lane];
        ushort4 r2 = ((const ushort4*)(vb + (size_t)p2.x * D_IN))[lane];
        ushort4 r3 = ((const ushort4*)(vb + (size_t)p3.x * D_IN))[lane];
        ushort4 r4 = ((const ushort4*)(vb + (size_t)p4.x * D_IN))[lane];
        ushort4 r5 = ((const ushort4*)(vb + (size_t)p5.x * D_IN))[lane];
        ushort4 r6 = ((const ushort4*)(vb + (size_t)p6.x * D_IN))[lane];
        ushort4 r7 = ((const ushort4*)(vb + (size_t)p7.x * D_IN))[lane];
        a0 += w0 * bf2f(r0.x) + w1 * bf2f(r1.x) + w2 * bf2f(r2.x) + w3 * bf2f(r3.x);
        a1 += w0 * bf2f(r0.y) + w1 * bf2f(r1.y) + w2 * bf2f(r2.y) + w3 * bf2f(r3.y);
        a2 += w0 * bf2f(r0.z) + w1 * bf2f(r1.z) + w2 * bf2f(r2.z) + w3 * bf2f(r3.z);
        a3 += w0 * bf2f(r0.w) + w1 * bf2f(r1.w) + w2 * bf2f(r2.w) + w3 * bf2f(r3.w);
        c0 += w4 * bf2f(r4.x) + w5 * bf2f(r5.x) + w6 * bf2f(r6.x) + w7 * bf2f(r7.x);
        c1 += w4 * bf2f(r4.y) + w5 * bf2f(r5.y) + w6 * bf2f(r6.y) + w7 * bf2f(r7.y);
        c2 += w4 * bf2f(r4.z) + w5 * bf2f(r5.z) + w6 * bf2f(r6.z) + w7 * bf2f(r7.z);
        c3 += w4 * bf2f(r4.w) + w5 * bf2f(r5.w) + w6 * bf2f(r6.w) + w7 * bf2f(r7.w);
    }
    for (; i + 4 <= end; i += 4) {
        int2 p0 = perm[i + 0], p1 = perm[i + 1], p2 = perm[i + 2], p3 = perm[i + 3];
        float w0 = __int_as_float(p0.y), w1 = __int_as_float(p1.y);
        float w2 = __int_as_float(p2.y), w3 = __int_as_float(p3.y);
        ushort4 r0 = ((const ushort4*)(vb + (size_t)p0.x * D_IN))[lane];
        ushort4 r1 = ((const ushort4*)(vb + (size_t)p1.x * D_IN))[lane];
        ushort4 r2 = ((const ushort4*)(vb + (size_t)p2.x * D_IN))[lane];
        ushort4 r3 = ((const ushort4*)(vb + (size_t)p3.x * D_IN))[lane];
        a0 += w0 * bf2f(r0.x) + w1 * bf2f(r1.x) + w2 * bf2f(r2.x) + w3 * bf2f(r3.x);
        a1 += w0 * bf2f(r0.y) + w1 * bf2f(r1.y) + w2 * bf2f(r2.y) + w3 * bf2f(r3.y);
        a2 += w0 * bf2f(r0.z) + w1 * bf2f(r1.z) + w2 * bf2f(r2.z) + w3 * bf2f(r3.z);
        a3 += w0 * bf2f(r0.w) + w1 * bf2f(r1.w) + w2 * bf2f(r2.w) + w3 * bf2f(r3.w);
    }
    for (; i < end; ++i) {
        int2 p = perm[i];
        float w = __int_as_float(p.y);
        ushort4 r = ((const ushort4*)(vb + (size_t)p.x * D_IN))[lane];
        a0 += w * bf2f(r.x); a1 += w * bf2f(r.y);
        a2 += w * bf2f(r.z); a3 += w * bf2f(r.w);
    }
    a0 += c0; a1 += c1; a2 += c2; a3 += c3;
    float eps = eps_p[0];
    ushort4 m = ((const ushort4*)(vb + (size_t)node * D_IN))[lane];
    a0 += eps * bf2f(m.x); a1 += eps * bf2f(m.y);
    a2 += eps * bf2f(m.z); a3 += eps * bf2f(m.w);
    ((ushort4*)(aggb + (size_t)node * D_IN))[lane] =
        make_ushort4(f2bf(a0), f2bf(a1), f2bf(a2), f2bf(a3));
}

// ---------------------------------------------------------------------------
// Fused MLP, 64-row tile, 512 threads / 8 waves (halves per-block serial work
// vs R6's 4-wave version; 16 waves/CU for latency hiding). Same reg-dbuf
// packed-B pipeline, barrier-free K-loops.
//  GEMM1: wave w -> cols [w*64, w*64+64), 16 MFMA/K-step.
//  GEMM2: wave w -> cols [w*32, w*32+32), 16 MFMA/K-step (2 k-halves).
// LDS: hs 64KB + redf 4.6KB = 70.1KB -> 2 blocks/CU.
// ---------------------------------------------------------------------------
#define HS_IDX(row, col) ((row) * 512 + ((col) ^ (((row) & 7) << 3)))
#define AT_IDX(row, col) ((row) * 256 + ((col) ^ (((row) & 7) << 3)))

__global__ __launch_bounds__(512, 4) void mlp_kernel(
    const ushort* __restrict__ A, const ushort* __restrict__ w1p,
    const ushort* __restrict__ w2p,
    const float* __restrict__ b1, const float* __restrict__ g1, const float* __restrict__ be1,
    const float* __restrict__ b2, const float* __restrict__ g2, const float* __restrict__ be2,
    float* __restrict__ out, int N) {
    __shared__ ushort hs[32768];      // 64 KB
    __shared__ float redf[1152];      // [0..511]=s [512..1023]=sq [1024..1087]=mu [1088..1151]=rs

    int t = threadIdx.x;
    int w = t >> 6, lane = t & 63;    // w in 0..7
    int row0 = blockIdx.x * 64;
    int fr = lane & 15, q = lane >> 4, kb = q * 8;

    // ---- stage A-tile once: 4 coalesced 1KB loads/wave, source-swizzled ----
    #pragma unroll
    for (int j = 0; j < 4; ++j) {
        int p = (w * 4 + j) * 64 + lane;          // chunk id 0..2047 (8 ushorts each)
        int row = p >> 5, cbs = p & 31;
        int colblk = cbs ^ (row & 7);             // inverse swizzle on source
        int ar = row0 + row; if (ar > N - 1) ar = N - 1;
        const ushort* gp = A + (size_t)ar * D_IN + colblk * 8;
        __builtin_amdgcn_global_load_lds(
            (const __attribute__((address_space(1))) void*)gp,
            (__attribute__((address_space(3))) void*)(&hs[(w * 4 + j) * 512]),
            16, 0, 0);
    }

    // ---- GEMM1: (64 x 256) @ w1^T -> 64 x 512, 8 K-steps, reg dbuf B ----
    bf16x8 bfb[2][4];
    #pragma unroll
    for (int c = 0; c < 4; ++c)       // prologue: B-frags for ks=0
        bfb[0][c] = *(const bf16x8*)(w1p + (size_t)(((0) * 32 + w * 4 + c) * 64 + lane) * 8);

    __syncthreads();                  // A-tile resident

    f32x4 acc[4][4];
    #pragma unroll
    for (int m = 0; m < 4; ++m)
        #pragma unroll
        for (int c = 0; c < 4; ++c) {
            f32x4 z = {0.f, 0.f, 0.f, 0.f};
            acc[m][c] = z;
        }

    #pragma unroll
    for (int ks = 0; ks < 8; ++ks) {
        const int cur = ks & 1, nxt = cur ^ 1;
        if (ks < 7) {                 // issue NEXT step's 4 B-loads before MFMAs
            #pragma unroll
            for (int c = 0; c < 4; ++c)
                bfb[nxt][c] = *(const bf16x8*)(w1p +
                    (size_t)(((ks + 1) * 32 + w * 4 + c) * 64 + lane) * 8);
        }
        bf16x8 af[4];
        #pragma unroll
        for (int m = 0; m < 4; ++m)
            af[m] = *(const bf16x8*)&hs[AT_IDX(m * 16 + fr, ks * 32 + kb)];
        #pragma unroll
        for (int m = 0; m < 4; ++m)
            #pragma unroll
            for (int c = 0; c < 4; ++c)
                acc[m][c] = __builtin_amdgcn_mfma_f32_16x16x32_bf16(af[m], bfb[cur][c], acc[m][c], 0, 0, 0);
    }

    // ------------- epilogue 1: bias + LN + ReLU -> Hs (LDS, swizzled) -------------
    {
        float bi[4], gg[4], bb[4];
        #pragma unroll
        for (int c = 0; c < 4; ++c) {
            int col = w * 64 + c * 16 + fr;
            bi[c] = b1[col]; gg[c] = g1[col]; bb[c] = be1[col];
        }
        #pragma unroll
        for (int m = 0; m < 4; ++m) {
            #pragma unroll
            for (int r = 0; r < 4; ++r) {
                float s = 0.f, sq = 0.f;
                #pragma unroll
                for (int c = 0; c < 4; ++c) {
                    float x = acc[m][c][r] + bi[c];
                    acc[m][c][r] = x;
                    s += x; sq += x * x;
                }
                #pragma unroll
                for (int o = 1; o < 16; o <<= 1) {
                    s  += __shfl_xor(s, o, 64);
                    sq += __shfl_xor(sq, o, 64);
                }
                if (fr == 0) {
                    int row = m * 16 + q * 4 + r;
                    redf[row * 8 + w]       = s;
                    redf[512 + row * 8 + w] = sq;
                }
            }
        }
        __syncthreads();              // all waves done with GEMM1 + A-tile reads
        if (t < 64) {
            float s = 0.f, sq = 0.f;
            #pragma unroll
            for (int k = 0; k < 8; ++k) {
                s  += redf[t * 8 + k];
                sq += redf[512 + t * 8 + k];
            }
            float mu = s / (float)D_HID;
            float var = sq / (float)D_HID - mu * mu;
            redf[1024 + t] = mu;
            redf[1088 + t] = rsqrtf(var + LN_EPS);
        }
        __syncthreads();
        #pragma unroll
        for (int m = 0; m < 4; ++m) {
            #pragma unroll
            for (int r = 0; r < 4; ++r) {
                int row = m * 16 + q * 4 + r;
                float mu = redf[1024 + row], rs = redf[1088 + row];
                #pragma unroll
                for (int c = 0; c < 4; ++c) {
                    int col = w * 64 + c * 16 + fr;
                    float y = (acc[m][c][r] - mu) * rs * gg[c] + bb[c];
                    hs[HS_IDX(row, col)] = f2bf(fmaxf(y, 0.f));
                }
            }
        }
    }

    // ---- GEMM2: (64 x 512) @ w2^T -> 64 x 256, K_STEP=64, reg dbuf B ----
    bf16x8 bf2b[2][2][2];             // [dbuf][c][k-half]
    #pragma unroll
    for (int c = 0; c < 2; ++c)       // prologue loads (independent of Hs)
        #pragma unroll
        for (int h = 0; h < 2; ++h)
            bf2b[0][c][h] = *(const bf16x8*)(w2p +
                (size_t)(((0 + h) * 16 + w * 2 + c) * 64 + lane) * 8);

    __syncthreads();                  // Hs complete before any wave reads it

    f32x4 acc2[4][2];
    #pragma unroll
    for (int m = 0; m < 4; ++m)
        #pragma unroll
        for (int c = 0; c < 2; ++c) {
            f32x4 z = {0.f, 0.f, 0.f, 0.f};
            acc2[m][c] = z;
        }

    #pragma unroll
    for (int s2 = 0; s2 < 8; ++s2) {  // k0 = s2*64
        const int cur = s2 & 1, nxt = cur ^ 1;
        if (s2 < 7) {
            #pragma unroll
            for (int c = 0; c < 2; ++c)
                #pragma unroll
                for (int h = 0; h < 2; ++h)
                    bf2b[nxt][c][h] = *(const bf16x8*)(w2p +
                        (size_t)(((2 * (s2 + 1) + h) * 16 + w * 2 + c) * 64 + lane) * 8);
        }
        bf16x8 af2[4][2];
        #pragma unroll
        for (int m = 0; m < 4; ++m)
            #pragma unroll
            for (int h = 0; h < 2; ++h)
                af2[m][h] = *(const bf16x8*)&hs[HS_IDX(m * 16 + fr, s2 * 64 + h * 32 + kb)];
        #pragma unroll
        for (int m = 0; m < 4; ++m)
            #pragma unroll
            for (int c = 0; c < 2; ++c)
                #pragma unroll
                for (int h = 0; h < 2; ++h)
                    acc2[m][c] = __builtin_amdgcn_mfma_f32_16x16x32_bf16(af2[m][h], bf2b[cur][c][h], acc2[m][c], 0, 0, 0);
    }

    // ------------- epilogue 2: bias + LN + ReLU -> out (fp32) -------------
    {
        float bi[2], gg[2], bb[2];
        #pragma unroll
        for (int c = 0; c < 2; ++c) {
            int col = w * 32 + c * 16 + fr;
            bi[c] = b2[col]; gg[c] = g2[col]; bb[c] = be2[col];
        }
        #pragma unroll
        for (int m = 0; m < 4; ++m) {
            #pragma unroll
            for (int r = 0; r < 4; ++r) {
                float s = 0.f, sq = 0.f;
                #pragma unroll
                for (int c = 0; c < 2; ++c) {
                    float x = acc2[m][c][r] + bi[c];
                    acc2[m][c][r] = x;
                    s += x; sq += x * x;
                }
                #pragma unroll
                for (int o = 1; o < 16; o <<= 1) {
                    s  += __shfl_xor(s, o, 64);
                    sq += __shfl_xor(sq, o, 64);
                }
                if (fr == 0) {
                    int row = m * 16 + q * 4 + r;
                    redf[row * 8 + w]       = s;
                    redf[512 + row * 8 + w] = sq;
                }
            }
        }
        __syncthreads();
        if (t < 64) {
            float s = 0.f, sq = 0.f;
            #pragma unroll
            for (int k = 0; k < 8; ++k) {
                s  += redf[t * 8 + k];
                sq += redf[512 + t * 8 + k];
            }
            float mu = s / (float)D_OUT;
            float var = sq / (float)D_OUT - mu * mu;
            redf[1024 + t] = mu;
            redf[1088 + t] = rsqrtf(var + LN_EPS);
        }
        __syncthreads();
        #pragma unroll
        for (int m = 0; m < 4; ++m) {
            #pragma unroll
            for (int r = 0; r < 4; ++r) {
                int row = m * 16 + q * 4 + r;
                int grow = row0 + row;
                if (grow >= N) continue;
                float mu = redf[1024 + row], rs = redf[1088 + row];
                #pragma unroll
                for (int c = 0; c < 2; ++c) {
                    int col = w * 32 + c * 16 + fr;
                    float y = (acc2[m][c][r] - mu) * rs * gg[c] + bb[c];
                    out[(size_t)grow * D_OUT + col] = fmaxf(y, 0.f);
                }
            }
        }
    }
}

// ---------------------------------------------------------------------------
extern "C" void kernel_launch(void* const* d_in, const int* in_sizes, int n_in,
                              void* d_out, int out_size, void* d_ws, size_t ws_size,
                              hipStream_t stream) {
    const float* v     = (const float*)d_in[0];
    const float* ew    = (const float*)d_in[1];
    const float* eps   = (const float*)d_in[2];
    const float* w1    = (const float*)d_in[3];
    const float* b1    = (const float*)d_in[4];
    const float* g1    = (const float*)d_in[5];
    const float* beta1 = (const float*)d_in[6];
    const float* w2    = (const float*)d_in[7];
    const float* b2    = (const float*)d_in[8];
    const float* g2    = (const float*)d_in[9];
    const float* beta2 = (const float*)d_in[10];
    const int*   src   = (const int*)d_in[11];
    const int*   dst   = (const int*)d_in[12];

    int N = in_sizes[0] / D_IN;     // 50000
    int E = in_sizes[1];            // 800000

    float* out = (float*)d_out;

    // workspace layout (256B-aligned chunks)
    char* ws = (char*)d_ws;
    size_t off = 0;
    ushort* vb   = (ushort*)(ws + off); off += (size_t)N * D_IN * 2;            // 25.6 MB
    ushort* aggb = (ushort*)(ws + off); off += (size_t)N * D_IN * 2;            // 25.6 MB
    ushort* w1p  = (ushort*)(ws + off); off += (size_t)D_HID * D_IN * 2;        // 256 KB
    ushort* w2p  = (ushort*)(ws + off); off += (size_t)D_OUT * D_HID * 2;       // 256 KB
    int* offs     = (int*)(ws + off); off += (size_t)(N + 256) * 4;
    int* cnt      = (int*)(ws + off); off += (size_t)(N + 256) * 4;             // zeroed
    int* bsum     = (int*)(ws + off); off += 1024;
    int* rank     = (int*)(ws + off); off += (size_t)E * 4;                     // 3.2 MB
    int2* perm    = (int2*)(ws + off); off += (size_t)E * 8;                    // 6.4 MB

    int n4v = N * (D_IN / 4);
    int bv = (n4v + 255) / 256;
    int bw = 256;                     // 65536 float4s of weights
    int be = (E + 255) / 256;
    int nb = (N + SCAN_B - 1) / SCAN_B;

    // 0) zero the histogram
    hipMemsetAsync(cnt, 0, (size_t)N * 4, stream);

    // 1) prep: casts + packed weights + edge hist/rank
    prep_kernel<<<bv + bw + be, 256, 0, stream>>>(v, w1, w2, vb, w1p, w2p,
                                                  dst, rank, cnt, n4v, E, bv, bw);

    // 2) CSR offsets (two-level scan, proven)
    scan1_kernel<<<nb, SCAN_B, 0, stream>>>(cnt, offs, bsum, N);
    scan3_kernel<<<nb, SCAN_B, 0, stream>>>(offs, bsum, N, E, nb);

    // 3) counting-sort fill (no atomics)
    fill_kernel<<<be, 256, 0, stream>>>(src, dst, ew, rank, offs, perm, E);

    // 4) aggregate (bf16 gather), high-TLP standalone
    aggregate_kernel<<<(N + 3) / 4, 256, 0, stream>>>(vb, eps, offs, perm, aggb, N);

    // 5) fused MLP (512 threads / 8 waves)
    int mblocks = (N + 63) / 64;
    mlp_kernel<<<mblocks, 512, 0, stream>>>(aggb, w1p, w2p,
                                            b1, g1, beta1, b2, g2, beta2, out, N);
}